// Round 3
// baseline (405.758 us; speedup 1.0000x reference)
//
#include <hip/hip_runtime.h>

typedef unsigned short u16;
typedef __bf16 __attribute__((ext_vector_type(8))) bf16x8;
typedef float __attribute__((ext_vector_type(4))) floatx4;

#define BH 4194304   // 2048*2048
#define HDIM 2048
#define KTOT 4096

__device__ __forceinline__ float bf2f(u16 u) {
  unsigned int v = ((unsigned int)u) << 16;
  return __builtin_bit_cast(float, v);
}
__device__ __forceinline__ u16 f2bf(float f) {
  unsigned int v = __builtin_bit_cast(unsigned int, f);
  unsigned int r = (v + 0x7fffu + ((v >> 16) & 1u)) >> 16;
  return (u16)r;
}
// packed f32->2xbf16 (RNE) in ONE VALU instruction
__device__ __forceinline__ unsigned cvtpk(float a, float b) {
  unsigned r;
  asm("v_cvt_pk_bf16_f32 %0, %1, %2" : "=v"(r) : "v"(a), "v"(b));
  return r;
}
__device__ __forceinline__ unsigned packu(unsigned lo, unsigned hi) {
  return (lo & 0xffffu) | (hi << 16);
}
__device__ __forceinline__ float sigm(float x) {
  return 1.f / (1.f + __expf(-x));
}

template <bool F32> struct Elt { using T = float; };
template <> struct Elt<false> { using T = u16; };

// register staging for one 64x64 K-tile slice (per thread)
template <bool F32> struct Stg;
template <> struct Stg<true>  { float4 a[4]; float2 b[8]; };   // 32 VGPR
template <> struct Stg<false> { uint4  a[2]; unsigned b[8]; }; // 16 VGPR

template <bool F32>
__device__ __forceinline__ float ldel(const void* p, size_t i) {
  if constexpr (F32) return ((const float*)p)[i];
  else return bf2f(((const u16*)p)[i]);
}
template <bool F32>
__device__ __forceinline__ void stel(void* p, size_t i, float v) {
  if constexpr (F32) ((float*)p)[i] = v;
  else ((u16*)p)[i] = f2bf(v);
}

// ---------------------------------------------------------------------------
// C[m][n] = sum_k Xcat[m][k]*Wcat[k][n], Xcat=[x|fd], Wcat=[wiv;wlat].
// BM=64, BN=64, BK=64, 256 thr = 4 waves (2x2), wave tile 32x32, 16x16x32 MFMA.
// Pipeline (1 barrier/iter, LDS double-buffered, 2 reg stages):
//   iter t: issue loads(tile t+2) -> MFMA(LDS[t&1]) ->
//           convert stage(tile t+1) -> LDS[(t+1)&1] -> barrier
// Loads for tile t+2 stay in flight ~1.5 iterations before their vmcnt wait.
// A: 2 rows/thread, k-contig float4 pairs.
// B: lane covers 2 consecutive n at 8 k-rows (float2 strided HDIM) ->
//    per-n k-contiguous packed LDS write. Swizzle: chunk c of row r at c^(r&7).
// XCD swizzle: 1024 blocks, XCD i owns lin [i*128, i*128+128) = 4 m-panels.
// ---------------------------------------------------------------------------
template <bool F32>
__device__ void glifr_body(
    const void* xv, const void* fdv, const void* wivv, const void* wlatv,
    const void* firingv, const void* voltagev, const void* ascv,
    const void* threshv, const void* tkmv, const void* tkjv,
    const void* trjv, const void* ajv, void* outv,
    u16* As0, u16* Bs0, u16* As1, u16* Bs1) {
  using El = typename Elt<F32>::T;
  const El* x    = (const El*)xv;
  const El* fd   = (const El*)fdv;
  const El* wiv  = (const El*)wivv;
  const El* wlat = (const El*)wlatv;

  const int tid  = threadIdx.x;
  const int lane = tid & 63;
  const int w    = tid >> 6;
  const int wm   = w >> 1;
  const int wn   = w & 1;

  const int b   = blockIdx.x;
  const int lin = (b & 7) * 128 + (b >> 3);   // XCD c owns lin [c*128, c*128+128)
  const int m0  = (lin >> 5) * 64;
  const int n0  = (lin & 31) * 64;

  int rowA[2], dgA[2];
#pragma unroll
  for (int i = 0; i < 2; ++i) {
    int slot = tid + i * 256;
    rowA[i] = slot >> 3;   // 0..63
    dgA[i]  = slot & 7;    // k-chunk
  }
  const int quad = lane >> 4;
  const int col  = lane & 15;
  const int kb8  = w * 16 + (lane >> 5) * 8;   // this thread's B k-row base
  const int chB  = w * 2 + (lane >> 5);        // B k-chunk 0..7
  const int ne   = 2 * (lane & 31);            // B n (even)

  floatx4 acc[2][2] = {};
  Stg<F32> S0, S1;

  // ---- helpers ----
  auto issueA = [&](Stg<F32>& st, const El* asrc) {
#pragma unroll
    for (int i = 0; i < 2; ++i) {
      const El* p = asrc + (size_t)(m0 + rowA[i]) * HDIM + dgA[i] * 8;
      if constexpr (F32) {
        st.a[2 * i]     = *(const float4*)p;
        st.a[2 * i + 1] = *(const float4*)(p + 4);
      } else {
        st.a[i] = *(const uint4*)p;
      }
    }
  };
  auto issueB = [&](Stg<F32>& st, const El* wsrc) {
    const El* p = wsrc + (size_t)kb8 * HDIM + n0 + ne;
#pragma unroll
    for (int j = 0; j < 8; ++j) {
      if constexpr (F32) st.b[j] = *(const float2*)(p + (size_t)j * HDIM);
      else               st.b[j] = *(const unsigned*)(p + (size_t)j * HDIM);
    }
  };
  auto writeTile = [&](Stg<F32>& st, u16* As, u16* Bs) {
#pragma unroll
    for (int i = 0; i < 2; ++i) {
      uint4 q;
      if constexpr (F32) {
        q.x = cvtpk(st.a[2 * i].x, st.a[2 * i].y);
        q.y = cvtpk(st.a[2 * i].z, st.a[2 * i].w);
        q.z = cvtpk(st.a[2 * i + 1].x, st.a[2 * i + 1].y);
        q.w = cvtpk(st.a[2 * i + 1].z, st.a[2 * i + 1].w);
      } else {
        q = st.a[i];
      }
      *(uint4*)&As[rowA[i] * 64 + ((dgA[i] ^ (rowA[i] & 7)) << 3)] = q;
    }
    uint4 qe, qo;
    if constexpr (F32) {
      qe.x = cvtpk(st.b[0].x, st.b[1].x);
      qe.y = cvtpk(st.b[2].x, st.b[3].x);
      qe.z = cvtpk(st.b[4].x, st.b[5].x);
      qe.w = cvtpk(st.b[6].x, st.b[7].x);
      qo.x = cvtpk(st.b[0].y, st.b[1].y);
      qo.y = cvtpk(st.b[2].y, st.b[3].y);
      qo.z = cvtpk(st.b[4].y, st.b[5].y);
      qo.w = cvtpk(st.b[6].y, st.b[7].y);
    } else {
      qe.x = packu(st.b[0], st.b[1]);
      qe.y = packu(st.b[2], st.b[3]);
      qe.z = packu(st.b[4], st.b[5]);
      qe.w = packu(st.b[6], st.b[7]);
      qo.x = (st.b[0] >> 16) | (st.b[1] & 0xffff0000u);
      qo.y = (st.b[2] >> 16) | (st.b[3] & 0xffff0000u);
      qo.z = (st.b[4] >> 16) | (st.b[5] & 0xffff0000u);
      qo.w = (st.b[6] >> 16) | (st.b[7] & 0xffff0000u);
    }
    *(uint4*)&Bs[ne * 64 + ((chB ^ (ne & 7)) << 3)]             = qe;
    *(uint4*)&Bs[(ne + 1) * 64 + ((chB ^ ((ne + 1) & 7)) << 3)] = qo;
  };
  auto mfmaPhase = [&](const u16* As, const u16* Bs) {
#pragma unroll
    for (int kk = 0; kk < 64; kk += 32) {
      bf16x8 af[2], bf[2];
#pragma unroll
      for (int mi = 0; mi < 2; ++mi) {
        const int r = wm * 32 + mi * 16 + col;
        const int p = ((kk >> 3) + quad) ^ (r & 7);
        af[mi] = *(const bf16x8*)&As[r * 64 + p * 8];
      }
#pragma unroll
      for (int ni = 0; ni < 2; ++ni) {
        const int r = wn * 32 + ni * 16 + col;
        const int p = ((kk >> 3) + quad) ^ (r & 7);
        bf[ni] = *(const bf16x8*)&Bs[r * 64 + p * 8];
      }
#pragma unroll
      for (int mi = 0; mi < 2; ++mi)
#pragma unroll
        for (int ni = 0; ni < 2; ++ni)
          acc[mi][ni] = __builtin_amdgcn_mfma_f32_16x16x32_bf16(
              af[mi], bf[ni], acc[mi][ni], 0, 0, 0);
    }
  };
  auto srcA = [&](int kn) -> const El* {
    return (kn < 2048) ? (x + kn) : (fd + (kn - 2048));
  };
  auto srcW = [&](int kn) -> const El* {
    return (kn < 2048) ? (wiv + (size_t)kn * HDIM)
                       : (wlat + (size_t)(kn - 2048) * HDIM);
  };

  // ---- prologue: tiles 0,1 ----
  issueA(S0, srcA(0));   issueB(S0, srcW(0));
  issueA(S1, srcA(64));  issueB(S1, srcW(64));
  writeTile(S0, As0, Bs0);
  __syncthreads();

  // ---- main loop, unrolled x2 for static stage/buffer roles ----
  for (int t = 0; t < 64; t += 2) {
    {  // even iter: compute tile t from buf0
      const int kn = (t + 2) * 64;
      if (kn < KTOT) { issueA(S0, srcA(kn)); issueB(S0, srcW(kn)); }
      mfmaPhase(As0, Bs0);
      writeTile(S1, As1, Bs1);           // tile t+1 (always valid, t<=62)
      __syncthreads();
    }
    {  // odd iter: compute tile t+1 from buf1
      const int kn = (t + 3) * 64;
      if (kn < KTOT) { issueA(S1, srcA(kn)); issueB(S1, srcW(kn)); }
      mfmaPhase(As1, Bs1);
      if ((t + 2) * 64 < KTOT) writeTile(S0, As0, Bs0);  // tile t+2
      __syncthreads();
    }
  }

  // ---- GLIFR epilogue ----  C/D: D[row = quad*4+i][col = lane&15]
  // DT/TAU=1, DT*k_j=sigmoid(tkj), DT*k_m=sigmoid(tkm), V_RESET=0
#pragma unroll
  for (int ni = 0; ni < 2; ++ni) {
    const int h = n0 + wn * 32 + ni * 16 + col;
    const float th  = ldel<F32>(threshv, h);
    const float sm  = sigm(ldel<F32>(tkmv, h));
    const float sk0 = sigm(ldel<F32>(tkjv, h));
    const float sk1 = sigm(ldel<F32>(tkjv, HDIM + h));
    const float r0  = 1.f - 2.f * sigm(ldel<F32>(trjv, h));
    const float r1  = 1.f - 2.f * sigm(ldel<F32>(trjv, HDIM + h));
    const float a0c = ldel<F32>(ajv, h);
    const float a1c = ldel<F32>(ajv, HDIM + h);
#pragma unroll
    for (int mi = 0; mi < 2; ++mi) {
#pragma unroll
      for (int i = 0; i < 4; ++i) {
        const int m = m0 + wm * 32 + mi * 16 + quad * 4 + i;
        const size_t idx = (size_t)m * HDIM + h;
        const float f   = ldel<F32>(firingv, idx);
        const float v   = ldel<F32>(voltagev, idx);
        const float A0  = ldel<F32>(ascv, idx);
        const float A1  = ldel<F32>(ascv, BH + idx);
        const float syn = acc[mi][ni][i];
        const float na0 = (A0 * r0 + a0c) * f + (1.f - sk0) * A0;
        const float na1 = (A1 * r1 + a1c) * f + (1.f - sk1) * A1;
        const float nv  = syn + sm * 0.1f * (na0 + na1 + 0.7f)
                          + (1.f - sm) * v - f * v;
        const float nf  = sigm(nv - th);
        stel<F32>(outv, idx,            nf);   // firing
        stel<F32>(outv, BH + idx,       nv);   // voltage
        stel<F32>(outv, 2 * BH + idx,   na0);  // ascurrent[0]
        stel<F32>(outv, 3 * BH + idx,   na1);  // ascurrent[1]
        stel<F32>(outv, 4 * BH + idx,   syn);  // syncurrent
      }
    }
  }
}

// ---------------------------------------------------------------------------
// Dtype detection: x ~ N(0,1). If the buffer is f32, its u16 view contains
// mantissa halves = ~uniform random bits -> some decode as huge/NaN bf16.
// If the buffer is bf16 N(0,1), |v| <= ~6 and exp field never saturates.
// ---------------------------------------------------------------------------
__device__ __forceinline__ bool detect_f32(const u16* xu) {
  bool wild = false;
  for (int i = (threadIdx.x & 63); i < 1024; i += 64) {
    const u16 u = xu[i];
    if ((u & 0x7f80u) == 0x7f80u || fabsf(bf2f(u)) > 64.f) wild = true;
  }
  return __any(wild);
}

__global__ __launch_bounds__(256, 4) void glifr_fused(
    const void* x, const void* fd, const void* wiv, const void* wlat,
    const void* firing, const void* voltage, const void* asc,
    const void* thresh, const void* tkm, const void* tkj, const void* trj,
    const void* aj, void* out) {
  __shared__ u16 As0[64 * 64];
  __shared__ u16 Bs0[64 * 64];
  __shared__ u16 As1[64 * 64];
  __shared__ u16 Bs1[64 * 64];
  if (detect_f32((const u16*)x)) {
    glifr_body<true>(x, fd, wiv, wlat, firing, voltage, asc, thresh, tkm,
                     tkj, trj, aj, out, As0, Bs0, As1, Bs1);
  } else {
    glifr_body<false>(x, fd, wiv, wlat, firing, voltage, asc, thresh, tkm,
                      tkj, trj, aj, out, As0, Bs0, As1, Bs1);
  }
}

extern "C" void kernel_launch(void* const* d_in, const int* in_sizes, int n_in,
                              void* d_out, int out_size, void* d_ws, size_t ws_size,
                              hipStream_t stream) {
  const void* x    = d_in[0];
  const void* fir  = d_in[1];
  const void* vol  = d_in[2];
  const void* asc  = d_in[3];
  // d_in[4] = syncurrent (unused, overwritten by reference)
  const void* fd   = d_in[5];
  const void* wiv  = d_in[6];
  const void* wlat = d_in[7];
  const void* th   = d_in[8];
  const void* tkm  = d_in[9];
  const void* tkj  = d_in[10];
  const void* trj  = d_in[11];
  const void* aj   = d_in[12];

  glifr_fused<<<dim3(1024), 256, 0, stream>>>(
      x, fd, wiv, wlat, fir, vol, asc, th, tkm, tkj, trj, aj, d_out);
}

// Round 4
// 393.247 us; speedup vs baseline: 1.0318x; 1.0318x over previous
//
#include <hip/hip_runtime.h>

typedef unsigned short u16;
typedef __bf16 __attribute__((ext_vector_type(8))) bf16x8;
typedef float __attribute__((ext_vector_type(4))) floatx4;

#define BH 4194304   // 2048*2048
#define HDIM 2048
#define KTOT 4096

__device__ __forceinline__ float bf2f(u16 u) {
  unsigned int v = ((unsigned int)u) << 16;
  return __builtin_bit_cast(float, v);
}
__device__ __forceinline__ u16 f2bf(float f) {
  unsigned int v = __builtin_bit_cast(unsigned int, f);
  unsigned int r = (v + 0x7fffu + ((v >> 16) & 1u)) >> 16;
  return (u16)r;
}
// packed f32->2xbf16 (RNE) in ONE VALU instruction
__device__ __forceinline__ unsigned cvtpk(float a, float b) {
  unsigned r;
  asm("v_cvt_pk_bf16_f32 %0, %1, %2" : "=v"(r) : "v"(a), "v"(b));
  return r;
}
__device__ __forceinline__ unsigned packu(u16 a, u16 b) {
  return (unsigned)a | ((unsigned)b << 16);
}
__device__ __forceinline__ float sigm(float x) {
  return 1.f / (1.f + __expf(-x));
}

template <bool F32> struct Elt { using T = float; };
template <> struct Elt<false> { using T = u16; };

// register staging for one 64x64 K-tile slice (per thread)
template <bool F32> struct Stg;
template <> struct Stg<true>  { float4 a[4]; float b[16]; };  // 32 VGPR
template <> struct Stg<false> { uint4  a[2]; u16   b[16]; };  // 16 VGPR

template <bool F32>
__device__ __forceinline__ float ldel(const void* p, size_t i) {
  if constexpr (F32) return ((const float*)p)[i];
  else return bf2f(((const u16*)p)[i]);
}
template <bool F32>
__device__ __forceinline__ void stel(void* p, size_t i, float v) {
  if constexpr (F32) ((float*)p)[i] = v;
  else ((u16*)p)[i] = f2bf(v);
}

// ---------------------------------------------------------------------------
// C[m][n] = sum_k Xcat[m][k]*Wcat[k][n], Xcat=[x|fd], Wcat=[wiv;wlat].
// BM=64, BN=64, BK=64, 256 thr = 4 waves (2x2), wave tile 32x32, 16x16x32 MFMA.
//
// R4 = R2's verified memory layout (2D grid n-fastest, FETCH 271MB,
//      0 bank conflicts) + R3's pipeline (LDS double-buffer, 2-deep register
//      staging, ONE barrier/iter):
//   iter t: issue loads(tile t+2) -> MFMA(LDS[t&1]) ->
//           convert stage(tile t+1) -> LDS[(t+1)&1] -> barrier
// Loads stay in flight ~1.5 iterations before their vmcnt wait.
// NO XCD swizzle (R3 measured +330MB FETCH = the whole regression).
// B global read: 16 scalar k-strided loads (wave = 256B/k-row).
// B LDS write: row = lane, chunk = (2w+c)^(lane&7) (measured conflict-free).
// ---------------------------------------------------------------------------
template <bool F32>
__device__ void glifr_body(
    const void* xv, const void* fdv, const void* wivv, const void* wlatv,
    const void* firingv, const void* voltagev, const void* ascv,
    const void* threshv, const void* tkmv, const void* tkjv,
    const void* trjv, const void* ajv, void* outv,
    u16* As0, u16* Bs0, u16* As1, u16* Bs1) {
  using El = typename Elt<F32>::T;
  const El* x    = (const El*)xv;
  const El* fd   = (const El*)fdv;
  const El* wiv  = (const El*)wivv;
  const El* wlat = (const El*)wlatv;

  const int tid  = threadIdx.x;
  const int lane = tid & 63;
  const int w    = tid >> 6;
  const int wm   = w >> 1;
  const int wn   = w & 1;
  const int m0   = blockIdx.y * 64;
  const int n0   = blockIdx.x * 64;

  int rowA[2], dgA[2];
#pragma unroll
  for (int i = 0; i < 2; ++i) {
    int slot = tid + i * 256;
    rowA[i] = slot >> 3;   // 0..63
    dgA[i]  = slot & 7;    // k-chunk
  }
  const int quad  = lane >> 4;
  const int col   = lane & 15;
  const int kbase = w * 16;  // this wave's B k-slice

  floatx4 acc[2][2] = {};
  Stg<F32> S0, S1;

  // ---- helpers ----
  auto issueA = [&](Stg<F32>& st, const El* asrc) {
#pragma unroll
    for (int i = 0; i < 2; ++i) {
      const El* p = asrc + (size_t)(m0 + rowA[i]) * HDIM + dgA[i] * 8;
      if constexpr (F32) {
        st.a[2 * i]     = *(const float4*)p;
        st.a[2 * i + 1] = *(const float4*)(p + 4);
      } else {
        st.a[i] = *(const uint4*)p;
      }
    }
  };
  auto issueB = [&](Stg<F32>& st, const El* wsrc) {
    const El* p = wsrc + (size_t)kbase * HDIM + n0 + lane;
#pragma unroll
    for (int j = 0; j < 16; ++j) st.b[j] = p[(size_t)j * HDIM];
  };
  auto writeTile = [&](Stg<F32>& st, u16* As, u16* Bs) {
#pragma unroll
    for (int i = 0; i < 2; ++i) {
      uint4 q;
      if constexpr (F32) {
        q.x = cvtpk(st.a[2 * i].x, st.a[2 * i].y);
        q.y = cvtpk(st.a[2 * i].z, st.a[2 * i].w);
        q.z = cvtpk(st.a[2 * i + 1].x, st.a[2 * i + 1].y);
        q.w = cvtpk(st.a[2 * i + 1].z, st.a[2 * i + 1].w);
      } else {
        q = st.a[i];
      }
      *(uint4*)&As[rowA[i] * 64 + ((dgA[i] ^ (rowA[i] & 7)) << 3)] = q;
    }
#pragma unroll
    for (int c = 0; c < 2; ++c) {
      uint4 q;
      if constexpr (F32) {
        q.x = cvtpk(st.b[8 * c + 0], st.b[8 * c + 1]);
        q.y = cvtpk(st.b[8 * c + 2], st.b[8 * c + 3]);
        q.z = cvtpk(st.b[8 * c + 4], st.b[8 * c + 5]);
        q.w = cvtpk(st.b[8 * c + 6], st.b[8 * c + 7]);
      } else {
        q.x = packu(st.b[8 * c + 0], st.b[8 * c + 1]);
        q.y = packu(st.b[8 * c + 2], st.b[8 * c + 3]);
        q.z = packu(st.b[8 * c + 4], st.b[8 * c + 5]);
        q.w = packu(st.b[8 * c + 6], st.b[8 * c + 7]);
      }
      const int ch = 2 * w + c;  // k-chunk 0..7
      *(uint4*)&Bs[lane * 64 + ((ch ^ (lane & 7)) << 3)] = q;
    }
  };
  auto mfmaPhase = [&](const u16* As, const u16* Bs) {
#pragma unroll
    for (int kk = 0; kk < 64; kk += 32) {
      bf16x8 af[2], bf[2];
#pragma unroll
      for (int mi = 0; mi < 2; ++mi) {
        const int r = wm * 32 + mi * 16 + col;
        const int p = ((kk >> 3) + quad) ^ (r & 7);
        af[mi] = *(const bf16x8*)&As[r * 64 + p * 8];
      }
#pragma unroll
      for (int ni = 0; ni < 2; ++ni) {
        const int r = wn * 32 + ni * 16 + col;
        const int p = ((kk >> 3) + quad) ^ (r & 7);
        bf[ni] = *(const bf16x8*)&Bs[r * 64 + p * 8];
      }
#pragma unroll
      for (int mi = 0; mi < 2; ++mi)
#pragma unroll
        for (int ni = 0; ni < 2; ++ni)
          acc[mi][ni] = __builtin_amdgcn_mfma_f32_16x16x32_bf16(
              af[mi], bf[ni], acc[mi][ni], 0, 0, 0);
    }
  };
  auto srcA = [&](int kn) -> const El* {
    return (kn < 2048) ? (x + kn) : (fd + (kn - 2048));
  };
  auto srcW = [&](int kn) -> const El* {
    return (kn < 2048) ? (wiv + (size_t)kn * HDIM)
                       : (wlat + (size_t)(kn - 2048) * HDIM);
  };

  // ---- prologue: tiles 0,1 ----
  issueA(S0, srcA(0));   issueB(S0, srcW(0));
  issueA(S1, srcA(64));  issueB(S1, srcW(64));
  writeTile(S0, As0, Bs0);
  __syncthreads();

  // ---- main loop, unrolled x2 for static stage/buffer roles ----
  for (int t = 0; t < 64; t += 2) {
    {  // even iter: compute tile t from buf0
      const int kn = (t + 2) * 64;
      if (kn < KTOT) { issueA(S0, srcA(kn)); issueB(S0, srcW(kn)); }
      mfmaPhase(As0, Bs0);
      writeTile(S1, As1, Bs1);           // tile t+1 (always valid, t<=62)
      __syncthreads();
    }
    {  // odd iter: compute tile t+1 from buf1
      const int kn = (t + 3) * 64;
      if (kn < KTOT) { issueA(S1, srcA(kn)); issueB(S1, srcW(kn)); }
      mfmaPhase(As1, Bs1);
      if ((t + 2) * 64 < KTOT) writeTile(S0, As0, Bs0);  // tile t+2
      __syncthreads();
    }
  }

  // ---- GLIFR epilogue ----  C/D: D[row = quad*4+i][col = lane&15]
  // DT/TAU=1, DT*k_j=sigmoid(tkj), DT*k_m=sigmoid(tkm), V_RESET=0
#pragma unroll
  for (int ni = 0; ni < 2; ++ni) {
    const int h = n0 + wn * 32 + ni * 16 + col;
    const float th  = ldel<F32>(threshv, h);
    const float sm  = sigm(ldel<F32>(tkmv, h));
    const float sk0 = sigm(ldel<F32>(tkjv, h));
    const float sk1 = sigm(ldel<F32>(tkjv, HDIM + h));
    const float r0  = 1.f - 2.f * sigm(ldel<F32>(trjv, h));
    const float r1  = 1.f - 2.f * sigm(ldel<F32>(trjv, HDIM + h));
    const float a0c = ldel<F32>(ajv, h);
    const float a1c = ldel<F32>(ajv, HDIM + h);
#pragma unroll
    for (int mi = 0; mi < 2; ++mi) {
#pragma unroll
      for (int i = 0; i < 4; ++i) {
        const int m = m0 + wm * 32 + mi * 16 + quad * 4 + i;
        const size_t idx = (size_t)m * HDIM + h;
        const float f   = ldel<F32>(firingv, idx);
        const float v   = ldel<F32>(voltagev, idx);
        const float A0  = ldel<F32>(ascv, idx);
        const float A1  = ldel<F32>(ascv, BH + idx);
        const float syn = acc[mi][ni][i];
        const float na0 = (A0 * r0 + a0c) * f + (1.f - sk0) * A0;
        const float na1 = (A1 * r1 + a1c) * f + (1.f - sk1) * A1;
        const float nv  = syn + sm * 0.1f * (na0 + na1 + 0.7f)
                          + (1.f - sm) * v - f * v;
        const float nf  = sigm(nv - th);
        stel<F32>(outv, idx,            nf);   // firing
        stel<F32>(outv, BH + idx,       nv);   // voltage
        stel<F32>(outv, 2 * BH + idx,   na0);  // ascurrent[0]
        stel<F32>(outv, 3 * BH + idx,   na1);  // ascurrent[1]
        stel<F32>(outv, 4 * BH + idx,   syn);  // syncurrent
      }
    }
  }
}

// ---------------------------------------------------------------------------
// Dtype detection: x ~ N(0,1). If the buffer is f32, its u16 view contains
// mantissa halves = ~uniform random bits -> some decode as huge/NaN bf16.
// If the buffer is bf16 N(0,1), |v| <= ~6 and exp field never saturates.
// ---------------------------------------------------------------------------
__device__ __forceinline__ bool detect_f32(const u16* xu) {
  bool wild = false;
  for (int i = (threadIdx.x & 63); i < 1024; i += 64) {
    const u16 u = xu[i];
    if ((u & 0x7f80u) == 0x7f80u || fabsf(bf2f(u)) > 64.f) wild = true;
  }
  return __any(wild);
}

__global__ __launch_bounds__(256, 4) void glifr_fused(
    const void* x, const void* fd, const void* wiv, const void* wlat,
    const void* firing, const void* voltage, const void* asc,
    const void* thresh, const void* tkm, const void* tkj, const void* trj,
    const void* aj, void* out) {
  __shared__ u16 As0[64 * 64];
  __shared__ u16 Bs0[64 * 64];
  __shared__ u16 As1[64 * 64];
  __shared__ u16 Bs1[64 * 64];
  if (detect_f32((const u16*)x)) {
    glifr_body<true>(x, fd, wiv, wlat, firing, voltage, asc, thresh, tkm,
                     tkj, trj, aj, out, As0, Bs0, As1, Bs1);
  } else {
    glifr_body<false>(x, fd, wiv, wlat, firing, voltage, asc, thresh, tkm,
                      tkj, trj, aj, out, As0, Bs0, As1, Bs1);
  }
}

extern "C" void kernel_launch(void* const* d_in, const int* in_sizes, int n_in,
                              void* d_out, int out_size, void* d_ws, size_t ws_size,
                              hipStream_t stream) {
  const void* x    = d_in[0];
  const void* fir  = d_in[1];
  const void* vol  = d_in[2];
  const void* asc  = d_in[3];
  // d_in[4] = syncurrent (unused, overwritten by reference)
  const void* fd   = d_in[5];
  const void* wiv  = d_in[6];
  const void* wlat = d_in[7];
  const void* th   = d_in[8];
  const void* tkm  = d_in[9];
  const void* tkj  = d_in[10];
  const void* trj  = d_in[11];
  const void* aj   = d_in[12];

  glifr_fused<<<dim3(32, 32), 256, 0, stream>>>(
      x, fd, wiv, wlat, fir, vol, asc, th, tkm, tkj, trj, aj, d_out);
}

// Round 5
// 328.087 us; speedup vs baseline: 1.2367x; 1.1986x over previous
//
#include <hip/hip_runtime.h>

typedef unsigned short u16;
typedef __bf16 __attribute__((ext_vector_type(8))) bf16x8;
typedef float __attribute__((ext_vector_type(4))) floatx4;

#define BH 4194304   // 2048*2048
#define HDIM 2048
#define KTOT 4096

__device__ __forceinline__ float bf2f(u16 u) {
  unsigned int v = ((unsigned int)u) << 16;
  return __builtin_bit_cast(float, v);
}
__device__ __forceinline__ u16 f2bf(float f) {
  unsigned int v = __builtin_bit_cast(unsigned int, f);
  unsigned int r = (v + 0x7fffu + ((v >> 16) & 1u)) >> 16;
  return (u16)r;
}
// packed f32->2xbf16 (RNE) in ONE VALU instruction
__device__ __forceinline__ unsigned cvtpk(float a, float b) {
  unsigned r;
  asm("v_cvt_pk_bf16_f32 %0, %1, %2" : "=v"(r) : "v"(a), "v"(b));
  return r;
}
__device__ __forceinline__ unsigned packu(u16 a, u16 b) {
  return (unsigned)a | ((unsigned)b << 16);
}
__device__ __forceinline__ float sigm(float x) {
  return 1.f / (1.f + __expf(-x));
}

template <bool F32> struct Elt { using T = float; };
template <> struct Elt<false> { using T = u16; };

// register staging for one 64x64 K-tile slice (per thread, 512 threads)
template <bool F32> struct Stg;
template <> struct Stg<true>  { float4 a[2]; float b[8]; };  // 16 VGPR
template <> struct Stg<false> { uint4  a;    u16   b[8]; };  // 8 VGPR

template <bool F32>
__device__ __forceinline__ float ldel(const void* p, size_t i) {
  if constexpr (F32) return ((const float*)p)[i];
  else return bf2f(((const u16*)p)[i]);
}
template <bool F32>
__device__ __forceinline__ void stel(void* p, size_t i, float v) {
  if constexpr (F32) ((float*)p)[i] = v;
  else ((u16*)p)[i] = f2bf(v);
}

// ---------------------------------------------------------------------------
// C[m][n] = sum_k Xcat[m][k]*Wcat[k][n], Xcat=[x|fd], Wcat=[wiv;wlat].
// BM=64, BN=64, BK=64, **512 thr = 8 waves (2m x 4n)**, wave tile 32x16.
//
// R5 = R2's verified structure (single LDS buffer, 2 barriers/iter, 1-deep
// staging, n-fastest 2D grid, FETCH ~250MB, 0 bank conflicts) with DOUBLED
// waves/block: 4 blocks/CU x 8 waves = 32 waves/CU = 100% thread occupancy
// (was 16 waves = 40%). Per-thread work halves; VGPR stays < 64 so 8
// waves/SIMD is allocatable (__launch_bounds__(512,8)).
// R3/R4 lesson: deep reg pipelines get sunk by the compiler at 64 VGPR —
// buy TLP instead of ILP.
// A: 1 slot/thread (row=tid>>3, chunk=tid&7), k-contig.
// B: wave w owns k-rows w*8..w*8+7; lane = n; 8 k-strided scalar loads ->
//    one k-contig uint4 -> Bs[lane][chunk w ^ (lane&7)] (measured 0-conflict).
// ---------------------------------------------------------------------------
template <bool F32>
__device__ void glifr_body(
    const void* xv, const void* fdv, const void* wivv, const void* wlatv,
    const void* firingv, const void* voltagev, const void* ascv,
    const void* threshv, const void* tkmv, const void* tkjv,
    const void* trjv, const void* ajv, void* outv,
    u16* As, u16* Bs) {
  using El = typename Elt<F32>::T;
  const El* x    = (const El*)xv;
  const El* fd   = (const El*)fdv;
  const El* wiv  = (const El*)wivv;
  const El* wlat = (const El*)wlatv;

  const int tid  = threadIdx.x;
  const int lane = tid & 63;
  const int w    = tid >> 6;      // 0..7
  const int wm   = w >> 2;        // 0..1  (m half)
  const int wn   = w & 3;         // 0..3  (n quarter)
  const int m0   = blockIdx.y * 64;
  const int n0   = blockIdx.x * 64;

  const int rowA = tid >> 3;      // 0..63
  const int dgA  = tid & 7;       // k-chunk 0..7
  const int quad = lane >> 4;
  const int col  = lane & 15;
  const int kbase = w * 8;        // this wave's B k-slice (8 rows)

  floatx4 acc[2] = {};
  Stg<F32> S;

  auto issueA = [&](const El* asrc) {
    const El* p = asrc + (size_t)(m0 + rowA) * HDIM + dgA * 8;
    if constexpr (F32) {
      S.a[0] = *(const float4*)p;
      S.a[1] = *(const float4*)(p + 4);
    } else {
      S.a = *(const uint4*)p;
    }
  };
  auto issueB = [&](const El* wsrc) {
    const El* p = wsrc + (size_t)kbase * HDIM + n0 + lane;
#pragma unroll
    for (int j = 0; j < 8; ++j) S.b[j] = p[(size_t)j * HDIM];
  };
  auto writeTile = [&]() {
    uint4 qa;
    if constexpr (F32) {
      qa.x = cvtpk(S.a[0].x, S.a[0].y);
      qa.y = cvtpk(S.a[0].z, S.a[0].w);
      qa.z = cvtpk(S.a[1].x, S.a[1].y);
      qa.w = cvtpk(S.a[1].z, S.a[1].w);
    } else {
      qa = S.a;
    }
    *(uint4*)&As[rowA * 64 + ((dgA ^ (rowA & 7)) << 3)] = qa;
    uint4 qb;
    if constexpr (F32) {
      qb.x = cvtpk(S.b[0], S.b[1]);
      qb.y = cvtpk(S.b[2], S.b[3]);
      qb.z = cvtpk(S.b[4], S.b[5]);
      qb.w = cvtpk(S.b[6], S.b[7]);
    } else {
      qb.x = packu(S.b[0], S.b[1]);
      qb.y = packu(S.b[2], S.b[3]);
      qb.z = packu(S.b[4], S.b[5]);
      qb.w = packu(S.b[6], S.b[7]);
    }
    *(uint4*)&Bs[lane * 64 + ((w ^ (lane & 7)) << 3)] = qb;
  };
  auto mfmaPhase = [&]() {
#pragma unroll
    for (int kk = 0; kk < 64; kk += 32) {
      bf16x8 af[2], bf;
#pragma unroll
      for (int mi = 0; mi < 2; ++mi) {
        const int r = wm * 32 + mi * 16 + col;
        const int p = ((kk >> 3) + quad) ^ (r & 7);
        af[mi] = *(const bf16x8*)&As[r * 64 + p * 8];
      }
      {
        const int r = wn * 16 + col;
        const int p = ((kk >> 3) + quad) ^ (r & 7);
        bf = *(const bf16x8*)&Bs[r * 64 + p * 8];
      }
#pragma unroll
      for (int mi = 0; mi < 2; ++mi)
        acc[mi] = __builtin_amdgcn_mfma_f32_16x16x32_bf16(
            af[mi], bf, acc[mi], 0, 0, 0);
    }
  };
  auto srcA = [&](int kn) -> const El* {
    return (kn < 2048) ? (x + kn) : (fd + (kn - 2048));
  };
  auto srcW = [&](int kn) -> const El* {
    return (kn < 2048) ? (wiv + (size_t)kn * HDIM)
                       : (wlat + (size_t)(kn - 2048) * HDIM);
  };

  // prologue: tile 0
  issueA(srcA(0));
  issueB(srcW(0));

  for (int kb = 0; kb < KTOT; kb += 64) {
    writeTile();
    if (kb + 64 < KTOT) {     // issue next tile; waits land at next writeTile
      issueA(srcA(kb + 64));
      issueB(srcW(kb + 64));
    }
    __syncthreads();
    mfmaPhase();
    __syncthreads();
  }

  // ---- GLIFR epilogue ----  C/D: D[row = quad*4+i][col = lane&15]
  // DT/TAU=1, DT*k_j=sigmoid(tkj), DT*k_m=sigmoid(tkm), V_RESET=0
  {
    const int h = n0 + wn * 16 + col;
    const float th  = ldel<F32>(threshv, h);
    const float sm  = sigm(ldel<F32>(tkmv, h));
    const float sk0 = sigm(ldel<F32>(tkjv, h));
    const float sk1 = sigm(ldel<F32>(tkjv, HDIM + h));
    const float r0  = 1.f - 2.f * sigm(ldel<F32>(trjv, h));
    const float r1  = 1.f - 2.f * sigm(ldel<F32>(trjv, HDIM + h));
    const float a0c = ldel<F32>(ajv, h);
    const float a1c = ldel<F32>(ajv, HDIM + h);
#pragma unroll
    for (int mi = 0; mi < 2; ++mi) {
#pragma unroll
      for (int i = 0; i < 4; ++i) {
        const int m = m0 + wm * 32 + mi * 16 + quad * 4 + i;
        const size_t idx = (size_t)m * HDIM + h;
        const float f   = ldel<F32>(firingv, idx);
        const float v   = ldel<F32>(voltagev, idx);
        const float A0  = ldel<F32>(ascv, idx);
        const float A1  = ldel<F32>(ascv, BH + idx);
        const float syn = acc[mi][i];
        const float na0 = (A0 * r0 + a0c) * f + (1.f - sk0) * A0;
        const float na1 = (A1 * r1 + a1c) * f + (1.f - sk1) * A1;
        const float nv  = syn + sm * 0.1f * (na0 + na1 + 0.7f)
                          + (1.f - sm) * v - f * v;
        const float nf  = sigm(nv - th);
        stel<F32>(outv, idx,            nf);   // firing
        stel<F32>(outv, BH + idx,       nv);   // voltage
        stel<F32>(outv, 2 * BH + idx,   na0);  // ascurrent[0]
        stel<F32>(outv, 3 * BH + idx,   na1);  // ascurrent[1]
        stel<F32>(outv, 4 * BH + idx,   syn);  // syncurrent
      }
    }
  }
}

// ---------------------------------------------------------------------------
// Dtype detection: x ~ N(0,1). If the buffer is f32, its u16 view contains
// mantissa halves = ~uniform random bits -> some decode as huge/NaN bf16.
// If the buffer is bf16 N(0,1), |v| <= ~6 and exp field never saturates.
// ---------------------------------------------------------------------------
__device__ __forceinline__ bool detect_f32(const u16* xu) {
  bool wild = false;
  for (int i = (threadIdx.x & 63); i < 1024; i += 64) {
    const u16 u = xu[i];
    if ((u & 0x7f80u) == 0x7f80u || fabsf(bf2f(u)) > 64.f) wild = true;
  }
  return __any(wild);
}

__global__ __launch_bounds__(512, 8) void glifr_fused(
    const void* x, const void* fd, const void* wiv, const void* wlat,
    const void* firing, const void* voltage, const void* asc,
    const void* thresh, const void* tkm, const void* tkj, const void* trj,
    const void* aj, void* out) {
  __shared__ u16 As[64 * 64];
  __shared__ u16 Bs[64 * 64];
  if (detect_f32((const u16*)x)) {
    glifr_body<true>(x, fd, wiv, wlat, firing, voltage, asc, thresh, tkm,
                     tkj, trj, aj, out, As, Bs);
  } else {
    glifr_body<false>(x, fd, wiv, wlat, firing, voltage, asc, thresh, tkm,
                      tkj, trj, aj, out, As, Bs);
  }
}

extern "C" void kernel_launch(void* const* d_in, const int* in_sizes, int n_in,
                              void* d_out, int out_size, void* d_ws, size_t ws_size,
                              hipStream_t stream) {
  const void* x    = d_in[0];
  const void* fir  = d_in[1];
  const void* vol  = d_in[2];
  const void* asc  = d_in[3];
  // d_in[4] = syncurrent (unused, overwritten by reference)
  const void* fd   = d_in[5];
  const void* wiv  = d_in[6];
  const void* wlat = d_in[7];
  const void* th   = d_in[8];
  const void* tkm  = d_in[9];
  const void* tkj  = d_in[10];
  const void* trj  = d_in[11];
  const void* aj   = d_in[12];

  glifr_fused<<<dim3(32, 32), 512, 0, stream>>>(
      x, fd, wiv, wlat, fir, vol, asc, th, tkm, tkj, trj, aj, d_out);
}